// Round 3
// baseline (1612.257 us; speedup 1.0000x reference)
//
#include <hip/hip_runtime.h>

#define NNODES 50000
#define HID 128
#define NREL 9
#define NLAYERS 3
#define NEDGES 600000

#define NBINS (NREL * NNODES)          // 450000, bin = r*NNODES + d  (r-major)
#define SCAN_CHUNK 1024
#define NBLK ((NBINS + SCAN_CHUNK - 1) / SCAN_CHUNK)   // 440

#define KTOT (NREL * HID)               // 1152
#define GM2 32                          // fused M-tile (rows per block) -> 1563 blocks
#define AP 132                          // f32 words per A-panel row (132%32=4 -> row spreads banks)
#define AWORDS (GM2 * AP)               // 4224 words = 16896 B per buffer
#define FPITCH 136                      // epilogue bf16 Et pitch (reuses AsF[0])

// prep_kernel block ranges
#define HIST_BLKS ((NEDGES + 255) / 256)            // 2344
#define EMB_BLKS  ((NNODES * HID / 8) / 256)        // 3125
#define W_BLKS    (NLAYERS * NREL)                  // 27

typedef __attribute__((ext_vector_type(8))) short short8;
typedef __attribute__((ext_vector_type(4))) float f32x4;

__device__ __forceinline__ short f2bf(float f) {
    union { float f; unsigned u; } c; c.f = f;
    unsigned r = c.u + 0x7fff + ((c.u >> 16) & 1);   // RNE
    return (short)(r >> 16);
}
__device__ __forceinline__ float bf2f(short v) {
    return __uint_as_float(((unsigned)(unsigned short)v) << 16);
}

// ---------------- prep: histogram + emb convert + W convert (one dispatch) ----------------
// Wt2[l][n][r*128+kk] = bf16(W[l][r][kk][n])   (r-major K)

__global__ __launch_bounds__(256) void prep_kernel(const int* __restrict__ dst,
                                                   const int* __restrict__ etype,
                                                   int* __restrict__ bins,
                                                   const float* __restrict__ E,
                                                   short* __restrict__ Ebf,
                                                   const float* __restrict__ W,
                                                   short* __restrict__ Wt2) {
    int b = blockIdx.x, tid = threadIdx.x;
    if (b < HIST_BLKS) {
        int e = b * 256 + tid;
        if (e < NEDGES) {
            int bin = etype[e] * NNODES + dst[e];
            atomicAdd(&bins[bin], 1);
        }
    } else if (b < HIST_BLKS + EMB_BLKS) {
        int gid = (b - HIST_BLKS) * 256 + tid;
        const float* p = E + (size_t)gid * 8;
        float4 v0 = *(const float4*)p;
        float4 v1 = *(const float4*)(p + 4);
        short8 o = {f2bf(v0.x), f2bf(v0.y), f2bf(v0.z), f2bf(v0.w),
                    f2bf(v1.x), f2bf(v1.y), f2bf(v1.z), f2bf(v1.w)};
        *(short8*)(Ebf + (size_t)gid * 8) = o;
    } else {
        int lr = b - HIST_BLKS - EMB_BLKS;
        int l = lr / NREL, r = lr - l * NREL;
        const float* w = W + (size_t)lr * HID * HID;
        short* o = Wt2 + (size_t)l * HID * KTOT;
#pragma unroll 4
        for (int i = 0; i < 64; i++) {
            int elem = i * 256 + tid;
            int kk = elem >> 7, n = elem & 127;
            o[(size_t)n * KTOT + r * HID + kk] = f2bf(w[elem]);
        }
    }
}

// ---------------- scans (unchanged) ----------------

__global__ __launch_bounds__(256) void scan_pass1(const int* __restrict__ bins,
                                                  int* __restrict__ blocksum) {
    __shared__ int red[256];
    int b = blockIdx.x, t = threadIdx.x;
    int i0 = b * SCAN_CHUNK + t * 4;
    int s = 0;
#pragma unroll
    for (int k = 0; k < 4; k++)
        if (i0 + k < NBINS) s += bins[i0 + k];
    red[t] = s;
    __syncthreads();
    for (int off = 128; off > 0; off >>= 1) {
        if (t < off) red[t] += red[t + off];
        __syncthreads();
    }
    if (t == 0) blocksum[b] = red[0];
}

__global__ __launch_bounds__(512) void scan_pass2(const int* __restrict__ blocksum,
                                                  int* __restrict__ blockoff,
                                                  int* __restrict__ rowptr) {
    __shared__ int s[512];
    int t = threadIdx.x;
    int v = (t < NBLK) ? blocksum[t] : 0;
    s[t] = v;
    __syncthreads();
    for (int off = 1; off < 512; off <<= 1) {
        int x = (t >= off) ? s[t - off] : 0;
        __syncthreads();
        s[t] += x;
        __syncthreads();
    }
    if (t < NBLK) blockoff[t] = s[t] - v;
    if (t == 0) rowptr[NBINS] = NEDGES;
}

__global__ __launch_bounds__(256) void scan_pass3(const int* __restrict__ bins,
                                                  const int* __restrict__ blockoff,
                                                  int* __restrict__ rowptr,
                                                  int* __restrict__ cursor) {
    __shared__ int sc[256];
    int b = blockIdx.x, t = threadIdx.x;
    int i0 = b * SCAN_CHUNK + t * 4;
    int v[4], p[4];
    int s = 0;
#pragma unroll
    for (int k = 0; k < 4; k++) {
        v[k] = (i0 + k < NBINS) ? bins[i0 + k] : 0;
        p[k] = s;
        s += v[k];
    }
    sc[t] = s;
    __syncthreads();
    for (int off = 1; off < 256; off <<= 1) {
        int x = (t >= off) ? sc[t - off] : 0;
        __syncthreads();
        sc[t] += x;
        __syncthreads();
    }
    int base = blockoff[b] + (sc[t] - s);
#pragma unroll
    for (int k = 0; k < 4; k++) {
        if (i0 + k < NBINS) {
            rowptr[i0 + k] = base + p[k];
            cursor[i0 + k] = base + p[k];
        }
    }
}

__global__ void place_kernel(const int* __restrict__ dst, const int* __restrict__ src,
                             const int* __restrict__ etype,
                             int* __restrict__ cursor,
                             int* __restrict__ bsrc, int* __restrict__ bdst) {
    int e = blockIdx.x * blockDim.x + threadIdx.x;
    if (e < NEDGES) {
        int d = dst[e];
        int bin = etype[e] * NNODES + d;
        int pos = atomicAdd(&cursor[bin], 1);
        bsrc[pos] = src[e];
        bdst[pos] = d;
    }
}

// ---------------- fused layer: edge-parallel gather (LDS f32 atomics) + GEMM ----------------
// Per block: 32 dest rows. Per relation r: the block's edges are the contiguous
// CSR range [rowptr[r*N+row0], rowptr[r*N+row0+32]). 32 edge-teams x 8 col-threads
// round-robin the range (max ~2 trips; no per-bin serial chains), ds_add_f32 into
// a f32 A-panel. Double-buffered panel, 2 barriers/relation; zero(cur) after barB
// is race-free (refill of cur at r+2 is separated by barA(r+1)).
// Banking: pitch 132 words (bank += 4*row); thread cols [cg*8..+7] & [64+cg*8..+7]
// -> atomic bank class (row%8, cg&3) = 32 classes / 64 lanes (~2-way).
// MFMA A-fragments read f32 LDS (balanced b128) + in-register f2bf convert.
// Wave shape 32Mx32N; C mapping: row = mt*16+lq*4+reg, col = n0+nt*16+lm (verified).

__global__ __launch_bounds__(256, 4) void fused_kernel(const short* __restrict__ Hin,
                                                       const short* __restrict__ Wt2l,
                                                       const float* __restrict__ Bias, // [9][128]
                                                       const int* __restrict__ rowptr,
                                                       const int* __restrict__ bsrc,
                                                       const int* __restrict__ bdst,
                                                       short* __restrict__ HoutBf,     // !last
                                                       float* __restrict__ HoutF,      // last
                                                       int last) {
    __shared__ float AsF[2][AWORDS];              // 2 x 16896 B; [0] reused as Et
    __shared__ int   rp_s[NREL * (GM2 + 1)];      // 297 ints
    __shared__ float bias_s[NREL * HID];          // 4608 B

    int tid  = threadIdx.x;
    int wave = tid >> 6, lane = tid & 63;
    int lm = lane & 15, lq = lane >> 4;
    int row0 = blockIdx.x * GM2;
    int n0   = wave * 32;                 // wave's N base
    int team = tid >> 3;                  // 0..31 edge slot
    int cg   = tid & 7;                   // col group

    // ---- prologue: prefetch first edge of relation 0 (direct rowptr reads) ----
    int rsb0 = rowptr[row0];                                  // rel-0 block range start
    int rebB = rowptr[(row0 + GM2 > NNODES) ? NNODES : (row0 + GM2)];
    int e_st = rsb0 + team;
    int stv  = (e_st < rebB);
    int st_row = 0;
    short8 sv0, sv1;
    if (stv) {
        int s = bsrc[e_st];
        st_row = bdst[e_st] - row0;
        const short* hb = Hin + (size_t)s * HID + cg * 8;
        sv0 = *(const short8*)hb;
        sv1 = *(const short8*)(hb + 64);
    }

    // stage rowptr spans and bias; zero both A-panels
    for (int i = tid; i < NREL * (GM2 + 1); i += 256) {
        int r = i / (GM2 + 1), o = i - r * (GM2 + 1);
        int d = row0 + o; if (d > NNODES) d = NNODES;
        rp_s[i] = rowptr[r * NNODES + d];
    }
    for (int i = tid; i < NREL * HID; i += 256) bias_s[i] = Bias[i];
    {
        float4 z = {0.f, 0.f, 0.f, 0.f};
        float4* zp = (float4*)&AsF[0][0];
        for (int i = tid; i < 2 * AWORDS / 4; i += 256) zp[i] = z;
    }

    f32x4 acc[2][2];
#pragma unroll
    for (int a = 0; a < 2; a++)
#pragma unroll
        for (int b = 0; b < 2; b++) acc[a][b] = (f32x4){0.f, 0.f, 0.f, 0.f};

    const short* wb = Wt2l + (size_t)(n0 + lm) * KTOT + lq * 8;

    __syncthreads();   // rp_s/bias/zeros visible

    for (int r = 0; r < NREL; r++) {
        float* Ap = &AsF[r & 1][0];

        // ---- B prefetch (L2-hot; latency hides under fill) ----
        short8 bfr[2][4];
#pragma unroll
        for (int nt = 0; nt < 2; nt++)
#pragma unroll
            for (int ks = 0; ks < 4; ks++)
                bfr[nt][ks] = *(const short8*)(wb + (size_t)nt * 16 * KTOT + r * HID + ks * 32);

        // ---- fill: edge-parallel atomics, 2-stage pipelined ----
        int reb = rp_s[r * (GM2 + 1) + GM2];
        int e = e_st;
        while (stv) {
            int e2 = e + 32;
            int nv = (e2 < reb);
            int row2 = 0; short8 w0, w1;
            if (nv) {                         // lookahead loads overlap current atomics
                int s2 = bsrc[e2];
                row2 = bdst[e2] - row0;
                const short* hb = Hin + (size_t)s2 * HID + cg * 8;
                w0 = *(const short8*)hb;
                w1 = *(const short8*)(hb + 64);
            }
            float* base = Ap + st_row * AP + cg * 8;
#pragma unroll
            for (int i = 0; i < 8; i++) atomicAdd(&base[i], bf2f(sv0[i]));
#pragma unroll
            for (int i = 0; i < 8; i++) atomicAdd(&base[64 + i], bf2f(sv1[i]));
            stv = nv;
            if (nv) { st_row = row2; sv0 = w0; sv1 = w1; e = e2; }
        }
        __syncthreads();   // barA: panel complete

        // ---- prefetch first edge of next relation (hides under MFMA+zero) ----
        if (r + 1 < NREL) {
            int nrsb = rp_s[(r + 1) * (GM2 + 1)];
            int nreb = rp_s[(r + 1) * (GM2 + 1) + GM2];
            e_st = nrsb + team;
            stv  = (e_st < nreb);
            if (stv) {
                int s = bsrc[e_st];
                st_row = bdst[e_st] - row0;
                const short* hb = Hin + (size_t)s * HID + cg * 8;
                sv0 = *(const short8*)hb;
                sv1 = *(const short8*)(hb + 64);
            }
        }

        // ---- MFMA: A from f32 LDS (convert in-register), B in registers ----
#pragma unroll
        for (int ks = 0; ks < 4; ks++) {
            const float4* pa0 = (const float4*)&Ap[lm * AP + ks * 32 + lq * 8];
            float4 x0 = pa0[0], x1 = pa0[1];
            const float4* pa1 = (const float4*)&Ap[(lm + 16) * AP + ks * 32 + lq * 8];
            float4 y0 = pa1[0], y1 = pa1[1];
            short8 af0 = {f2bf(x0.x), f2bf(x0.y), f2bf(x0.z), f2bf(x0.w),
                          f2bf(x1.x), f2bf(x1.y), f2bf(x1.z), f2bf(x1.w)};
            short8 af1 = {f2bf(y0.x), f2bf(y0.y), f2bf(y0.z), f2bf(y0.w),
                          f2bf(y1.x), f2bf(y1.y), f2bf(y1.z), f2bf(y1.w)};
            __builtin_amdgcn_s_setprio(1);
            acc[0][0] = __builtin_amdgcn_mfma_f32_16x16x32_bf16(af0, bfr[0][ks], acc[0][0], 0, 0, 0);
            acc[1][0] = __builtin_amdgcn_mfma_f32_16x16x32_bf16(af1, bfr[0][ks], acc[1][0], 0, 0, 0);
            acc[0][1] = __builtin_amdgcn_mfma_f32_16x16x32_bf16(af0, bfr[1][ks], acc[0][1], 0, 0, 0);
            acc[1][1] = __builtin_amdgcn_mfma_f32_16x16x32_bf16(af1, bfr[1][ks], acc[1][1], 0, 0, 0);
            __builtin_amdgcn_s_setprio(0);
        }
        __syncthreads();   // barB: panel reads done

        // ---- zero cur for its reuse at r+2 (race-free: see header comment) ----
        if (r + 2 < NREL) {
            float4 z = {0.f, 0.f, 0.f, 0.f};
            float4* zp = (float4*)Ap;
            for (int i = tid; i < AWORDS / 4; i += 256) zp[i] = z;
        }
    }

    // ---- epilogue: counts-weighted bias, activation, store ----
    if (!last) {
        short (*Et)[FPITCH] = (short(*)[FPITCH])&AsF[0][0];   // buf0 free after barB(8)
#pragma unroll
        for (int mt = 0; mt < 2; mt++) {
#pragma unroll
            for (int reg = 0; reg < 4; reg++) {
                int rl = mt * 16 + lq * 4 + reg;
                float cr[NREL];
#pragma unroll
                for (int rr = 0; rr < NREL; rr++)
                    cr[rr] = (float)(rp_s[rr * (GM2 + 1) + rl + 1] - rp_s[rr * (GM2 + 1) + rl]);
#pragma unroll
                for (int nt = 0; nt < 2; nt++) {
                    int n = n0 + nt * 16 + lm;
                    float b = 0.f;
#pragma unroll
                    for (int rr = 0; rr < NREL; rr++) b += cr[rr] * bias_s[rr * HID + n];
                    float o = fmaxf(acc[mt][nt][reg] + b, 0.f);
                    Et[rl][n] = f2bf(o);
                }
            }
        }
        __syncthreads();
#pragma unroll
        for (int i = 0; i < 2; i++) {
            int p = i * 256 + tid;
            int row = p >> 4, cc = p & 15;
            int d = row0 + row;
            if (d < NNODES)
                *(short8*)(HoutBf + (size_t)d * HID + cc * 8) = *(const short8*)&Et[row][cc * 8];
        }
    } else {
#pragma unroll
        for (int mt = 0; mt < 2; mt++) {
#pragma unroll
            for (int reg = 0; reg < 4; reg++) {
                int rl = mt * 16 + lq * 4 + reg;
                int d  = row0 + rl;
                if (d >= NNODES) continue;
                float cr[NREL];
#pragma unroll
                for (int rr = 0; rr < NREL; rr++)
                    cr[rr] = (float)(rp_s[rr * (GM2 + 1) + rl + 1] - rp_s[rr * (GM2 + 1) + rl]);
#pragma unroll
                for (int nt = 0; nt < 2; nt++) {
                    int n = n0 + nt * 16 + lm;
                    float b = 0.f;
#pragma unroll
                    for (int rr = 0; rr < NREL; rr++) b += cr[rr] * bias_s[rr * HID + n];
                    HoutF[(size_t)d * HID + n] = acc[mt][nt][reg] + b;
                }
            }
        }
    }
}

// ---------------- driver ----------------

extern "C" void kernel_launch(void* const* d_in, const int* in_sizes, int n_in,
                              void* d_out, int out_size, void* d_ws, size_t ws_size,
                              hipStream_t stream) {
    const int*   edge_index = (const int*)d_in[0];   // [2, NEDGES]: row0=dest, row1=src
    const int*   etype      = (const int*)d_in[1];
    const float* emb        = (const float*)d_in[2];
    const float* W          = (const float*)d_in[3]; // [3,9,128,128]
    const float* Bias       = (const float*)d_in[4]; // [3,9,128]
    float*       out        = (float*)d_out;

    const int* dst  = edge_index;
    const int* srcA = edge_index + NEDGES;

    // ws layout
    short* Ebf  = (short*)d_ws;                             // 50000*128 bf16
    short* HbfA = Ebf  + (size_t)NNODES * HID;              // 50000*128 bf16
    short* HbfB = HbfA + (size_t)NNODES * HID;              // 50000*128 bf16
    short* Wt2  = HbfB + (size_t)NNODES * HID;              // 3*128*1152 bf16
    int*   bsrc     = (int*)(Wt2 + (size_t)NLAYERS * HID * KTOT);
    int*   bdst     = bsrc + NEDGES;
    int*   bins     = bdst + NEDGES;
    int*   cursor   = bins + NBINS;
    int*   rowptr   = cursor + NBINS;                       // NBINS+1
    int*   blocksum = rowptr + NBINS + 1;
    int*   blockoff = blocksum + NBLK;

    hipMemsetAsync(bins, 0, NBINS * sizeof(int), stream);
    prep_kernel<<<HIST_BLKS + EMB_BLKS + W_BLKS, 256, 0, stream>>>(
        dst, etype, bins, emb, Ebf, W, Wt2);
    scan_pass1<<<NBLK, 256, 0, stream>>>(bins, blocksum);
    scan_pass2<<<1, 512, 0, stream>>>(blocksum, blockoff, rowptr);
    scan_pass3<<<NBLK, 256, 0, stream>>>(bins, blockoff, rowptr, cursor);
    place_kernel<<<(NEDGES + 255) / 256, 256, 0, stream>>>(dst, srcA, etype, cursor, bsrc, bdst);

    const int nblocks = (NNODES + GM2 - 1) / GM2;   // 1563
    const short* Hin = Ebf;
    for (int l = 0; l < NLAYERS; l++) {
        int last = (l + 1 == NLAYERS);
        short* Hout = (l == 0) ? HbfA : HbfB;       // alternate; never in-place
        if (l == 2) Hout = HbfA;                    // unused on last layer
        const short* Wtl = Wt2 + (size_t)l * HID * KTOT;
        const float* Bl  = Bias + (size_t)l * NREL * HID;
        fused_kernel<<<nblocks, 256, 0, stream>>>(
            Hin, Wtl, Bl, rowptr, bsrc, bdst, Hout, out, last);
        Hin = Hout;
    }
}

// Round 4
// 492.502 us; speedup vs baseline: 3.2736x; 3.2736x over previous
//
#include <hip/hip_runtime.h>

#define NNODES 50000
#define HID 128
#define NREL 9
#define NLAYERS 3
#define NEDGES 600000

#define NBINS (NREL * NNODES)          // 450000, bin = r*NNODES + d  (r-major)
#define SCAN_CHUNK 1024
#define NBLK ((NBINS + SCAN_CHUNK - 1) / SCAN_CHUNK)   // 440

#define KTOT (NREL * HID)               // 1152
#define GM2 32                          // rows per block -> 1563 blocks
#define KPITCH 1160                     // panel pitch in shorts (2320 B rows; 580%32=4 -> spread)
#define FPITCH 136                      // epilogue bf16 Et pitch (reuses As)

// prep_kernel block ranges
#define HIST_BLKS ((NEDGES + 255) / 256)            // 2344
#define EMB_BLKS  ((NNODES * HID / 8) / 256)        // 3125
#define W_BLKS    (NLAYERS * NREL)                  // 27

typedef __attribute__((ext_vector_type(8))) short short8;
typedef __attribute__((ext_vector_type(4))) float f32x4;

__device__ __forceinline__ short f2bf(float f) {
    union { float f; unsigned u; } c; c.f = f;
    unsigned r = c.u + 0x7fff + ((c.u >> 16) & 1);   // RNE
    return (short)(r >> 16);
}
__device__ __forceinline__ float bf2f(short v) {
    return __uint_as_float(((unsigned)(unsigned short)v) << 16);
}

// ---------------- prep: histogram + emb convert + W convert (one dispatch) ----------------
// Wt2[l][n][r*128+kk] = bf16(W[l][r][kk][n])   (r-major K)

__global__ __launch_bounds__(256) void prep_kernel(const int* __restrict__ dst,
                                                   const int* __restrict__ etype,
                                                   int* __restrict__ bins,
                                                   const float* __restrict__ E,
                                                   short* __restrict__ Ebf,
                                                   const float* __restrict__ W,
                                                   short* __restrict__ Wt2) {
    int b = blockIdx.x, tid = threadIdx.x;
    if (b < HIST_BLKS) {
        int e = b * 256 + tid;
        if (e < NEDGES) {
            int bin = etype[e] * NNODES + dst[e];
            atomicAdd(&bins[bin], 1);
        }
    } else if (b < HIST_BLKS + EMB_BLKS) {
        int gid = (b - HIST_BLKS) * 256 + tid;
        const float* p = E + (size_t)gid * 8;
        float4 v0 = *(const float4*)p;
        float4 v1 = *(const float4*)(p + 4);
        short8 o = {f2bf(v0.x), f2bf(v0.y), f2bf(v0.z), f2bf(v0.w),
                    f2bf(v1.x), f2bf(v1.y), f2bf(v1.z), f2bf(v1.w)};
        *(short8*)(Ebf + (size_t)gid * 8) = o;
    } else {
        int lr = b - HIST_BLKS - EMB_BLKS;
        int l = lr / NREL, r = lr - l * NREL;
        const float* w = W + (size_t)lr * HID * HID;
        short* o = Wt2 + (size_t)l * HID * KTOT;
#pragma unroll 4
        for (int i = 0; i < 64; i++) {
            int elem = i * 256 + tid;
            int kk = elem >> 7, n = elem & 127;
            o[(size_t)n * KTOT + r * HID + kk] = f2bf(w[elem]);
        }
    }
}

// ---------------- scans ----------------

__global__ __launch_bounds__(256) void scan_pass1(const int* __restrict__ bins,
                                                  int* __restrict__ blocksum) {
    __shared__ int red[256];
    int b = blockIdx.x, t = threadIdx.x;
    int i0 = b * SCAN_CHUNK + t * 4;
    int s = 0;
#pragma unroll
    for (int k = 0; k < 4; k++)
        if (i0 + k < NBINS) s += bins[i0 + k];
    red[t] = s;
    __syncthreads();
    for (int off = 128; off > 0; off >>= 1) {
        if (t < off) red[t] += red[t + off];
        __syncthreads();
    }
    if (t == 0) blocksum[b] = red[0];
}

__global__ __launch_bounds__(512) void scan_pass2(const int* __restrict__ blocksum,
                                                  int* __restrict__ blockoff,
                                                  int* __restrict__ rowptr) {
    __shared__ int s[512];
    int t = threadIdx.x;
    int v = (t < NBLK) ? blocksum[t] : 0;
    s[t] = v;
    __syncthreads();
    for (int off = 1; off < 512; off <<= 1) {
        int x = (t >= off) ? s[t - off] : 0;
        __syncthreads();
        s[t] += x;
        __syncthreads();
    }
    if (t < NBLK) blockoff[t] = s[t] - v;
    if (t == 0) rowptr[NBINS] = NEDGES;
}

__global__ __launch_bounds__(256) void scan_pass3(const int* __restrict__ bins,
                                                  const int* __restrict__ blockoff,
                                                  int* __restrict__ rowptr,
                                                  int* __restrict__ cursor) {
    __shared__ int sc[256];
    int b = blockIdx.x, t = threadIdx.x;
    int i0 = b * SCAN_CHUNK + t * 4;
    int v[4], p[4];
    int s = 0;
#pragma unroll
    for (int k = 0; k < 4; k++) {
        v[k] = (i0 + k < NBINS) ? bins[i0 + k] : 0;
        p[k] = s;
        s += v[k];
    }
    sc[t] = s;
    __syncthreads();
    for (int off = 1; off < 256; off <<= 1) {
        int x = (t >= off) ? sc[t - off] : 0;
        __syncthreads();
        sc[t] += x;
        __syncthreads();
    }
    int base = blockoff[b] + (sc[t] - s);
#pragma unroll
    for (int k = 0; k < 4; k++) {
        if (i0 + k < NBINS) {
            rowptr[i0 + k] = base + p[k];
            cursor[i0 + k] = base + p[k];
        }
    }
}

__global__ void place_kernel(const int* __restrict__ dst, const int* __restrict__ src,
                             const int* __restrict__ etype,
                             int* __restrict__ cursor, int* __restrict__ bsrc) {
    int e = blockIdx.x * blockDim.x + threadIdx.x;
    if (e < NEDGES) {
        int bin = etype[e] * NNODES + dst[e];
        int pos = atomicAdd(&cursor[bin], 1);
        bsrc[pos] = src[e];
    }
}

// ---------------- fused layer: single-phase gather + full-K MFMA sweep ----------------
// Per block: 32 dest rows. ONE gather phase covers all 9 relations (288 bins,
// ~384 edges): 64 teams x 4 threads (32 cols each), register accumulation with
// 4-deep masked edge groups (4 H-row loads in flight). Panel = full K=1152
// bf16 in LDS (74 KB). Then ONE barrier -> 36-chunk MFMA sweep (B streamed
// from L2, 2 m-tiles reuse each B-frag) -> epilogue. 3 barriers total.
// Team mapping: team<32 -> row=team, rels {0,2,4,6,8}; team>=32 -> row=team-32,
// rels {1,3,5,7}. Each (row,rel,colgroup) has exactly one owner (panel fully
// written, zero bins -> zeros). K order = r*128+kk, identical to round-2 sum order.
// Wave shape 32Mx32N; C mapping: row = mt*16+lq*4+reg, col = n0+nt*16+lm (verified).

__global__ __launch_bounds__(256, 2) void fused_kernel(const short* __restrict__ Hin,
                                                       const short* __restrict__ Wt2l,
                                                       const float* __restrict__ Bias, // [9][128]
                                                       const int* __restrict__ rowptr,
                                                       const int* __restrict__ bsrc,
                                                       short* __restrict__ HoutBf,     // !last
                                                       float* __restrict__ HoutF,      // last
                                                       int last) {
    __shared__ short As[GM2 * KPITCH];            // 74240 B; reused as Et
    __shared__ int   rp_s[NREL * (GM2 + 1)];      // 297 ints
    __shared__ float bias_s[NREL * HID];          // 4608 B

    int tid  = threadIdx.x;
    int wave = tid >> 6, lane = tid & 63;
    int lm = lane & 15, lq = lane >> 4;
    int row0 = blockIdx.x * GM2;
    int n0   = wave * 32;                 // wave's N base

    for (int i = tid; i < NREL * (GM2 + 1); i += 256) {
        int r = i / (GM2 + 1), o = i - r * (GM2 + 1);
        int d = row0 + o; if (d > NNODES) d = NNODES;   // clamp -> cnt 0 for pad rows
        rp_s[i] = rowptr[r * NNODES + d];
    }
    for (int i = tid; i < NREL * HID; i += 256) bias_s[i] = Bias[i];
    __syncthreads();

    // ---- gather phase: all relations, register accumulation ----
    int team = tid >> 2;          // 0..63
    int cg   = tid & 3;           // 32-col group
    int grow = team & 31;         // panel row
    int nbin = (team < 32) ? 5 : 4;
    int r0g  = (team < 32) ? 0 : 1;
    const short* hb = Hin + cg * 32;

    for (int bj = 0; bj < nbin; bj++) {
        int rr = r0g + bj * 2;
        int rs = rp_s[rr * (GM2 + 1) + grow];
        int re = rp_s[rr * (GM2 + 1) + grow + 1];
        float a[32];
#pragma unroll
        for (int i = 0; i < 32; i++) a[i] = 0.f;

        for (int i = rs; i < re; i += 4) {
            int rem = re - i;
            int i1 = (rem > 1) ? i + 1 : i;
            int i2 = (rem > 2) ? i + 2 : i;
            int i3 = (rem > 3) ? i + 3 : i;
            int s0 = bsrc[i], s1 = bsrc[i1], s2 = bsrc[i2], s3 = bsrc[i3];
            const short8* p0 = (const short8*)(hb + (size_t)s0 * HID);
            const short8* p1 = (const short8*)(hb + (size_t)s1 * HID);
            const short8* p2 = (const short8*)(hb + (size_t)s2 * HID);
            const short8* p3 = (const short8*)(hb + (size_t)s3 * HID);
            short8 v0[4] = {p0[0], p0[1], p0[2], p0[3]};   // 4 loads in flight
            short8 v1[4] = {p1[0], p1[1], p1[2], p1[3]};
            short8 v2[4] = {p2[0], p2[1], p2[2], p2[3]};
            short8 v3[4] = {p3[0], p3[1], p3[2], p3[3]};
            float m1 = (rem > 1) ? 1.f : 0.f;
            float m2 = (rem > 2) ? 1.f : 0.f;
            float m3 = (rem > 3) ? 1.f : 0.f;
#pragma unroll
            for (int q = 0; q < 4; q++)
#pragma unroll
                for (int k = 0; k < 8; k++) {
                    float t0 = bf2f(v0[q][k]) + m1 * bf2f(v1[q][k]);
                    float t1 = m2 * bf2f(v2[q][k]) + m3 * bf2f(v3[q][k]);
                    a[q * 8 + k] += t0 + t1;
                }
        }
        // write bin slice: row grow, cols rr*128 + cg*32 .. +31
        short8* ap = (short8*)&As[grow * KPITCH + rr * HID + cg * 32];
#pragma unroll
        for (int q = 0; q < 4; q++) {
            short8 o;
#pragma unroll
            for (int k = 0; k < 8; k++) o[k] = f2bf(a[q * 8 + k]);
            ap[q] = o;
        }
    }
    __syncthreads();   // panel complete

    // ---- MFMA sweep: A from LDS, B streamed from L2 (each frag feeds 2 MFMAs) ----
    f32x4 acc[2][2];
#pragma unroll
    for (int a = 0; a < 2; a++)
#pragma unroll
        for (int b = 0; b < 2; b++) acc[a][b] = (f32x4){0.f, 0.f, 0.f, 0.f};

    const short* wb0 = Wt2l + (size_t)(n0 + lm) * KTOT + lq * 8;
    const short* wb1 = wb0 + (size_t)16 * KTOT;

#pragma unroll 4
    for (int kc = 0; kc < KTOT / 32; kc++) {      // 36 chunks
        short8 b0 = *(const short8*)(wb0 + kc * 32);
        short8 b1 = *(const short8*)(wb1 + kc * 32);
        short8 a0 = *(const short8*)&As[(lm     ) * KPITCH + kc * 32 + lq * 8];
        short8 a1 = *(const short8*)&As[(lm + 16) * KPITCH + kc * 32 + lq * 8];
        __builtin_amdgcn_s_setprio(1);
        acc[0][0] = __builtin_amdgcn_mfma_f32_16x16x32_bf16(a0, b0, acc[0][0], 0, 0, 0);
        acc[1][0] = __builtin_amdgcn_mfma_f32_16x16x32_bf16(a1, b0, acc[1][0], 0, 0, 0);
        acc[0][1] = __builtin_amdgcn_mfma_f32_16x16x32_bf16(a0, b1, acc[0][1], 0, 0, 0);
        acc[1][1] = __builtin_amdgcn_mfma_f32_16x16x32_bf16(a1, b1, acc[1][1], 0, 0, 0);
        __builtin_amdgcn_s_setprio(0);
    }
    __syncthreads();   // panel reads done; safe to reuse As as Et

    // ---- epilogue: counts-weighted bias, activation, store ----
    if (!last) {
        short (*Et)[FPITCH] = (short(*)[FPITCH])&As[0];
#pragma unroll
        for (int mt = 0; mt < 2; mt++) {
#pragma unroll
            for (int reg = 0; reg < 4; reg++) {
                int rl = mt * 16 + lq * 4 + reg;
                float cr[NREL];
#pragma unroll
                for (int rr = 0; rr < NREL; rr++)
                    cr[rr] = (float)(rp_s[rr * (GM2 + 1) + rl + 1] - rp_s[rr * (GM2 + 1) + rl]);
#pragma unroll
                for (int nt = 0; nt < 2; nt++) {
                    int n = n0 + nt * 16 + lm;
                    float b = 0.f;
#pragma unroll
                    for (int rr = 0; rr < NREL; rr++) b += cr[rr] * bias_s[rr * HID + n];
                    float o = fmaxf(acc[mt][nt][reg] + b, 0.f);
                    Et[rl][n] = f2bf(o);
                }
            }
        }
        __syncthreads();
#pragma unroll
        for (int i = 0; i < 2; i++) {
            int p = i * 256 + tid;
            int row = p >> 4, cc = p & 15;
            int d = row0 + row;
            if (d < NNODES)
                *(short8*)(HoutBf + (size_t)d * HID + cc * 8) = *(const short8*)&Et[row][cc * 8];
        }
    } else {
#pragma unroll
        for (int mt = 0; mt < 2; mt++) {
#pragma unroll
            for (int reg = 0; reg < 4; reg++) {
                int rl = mt * 16 + lq * 4 + reg;
                int d  = row0 + rl;
                if (d >= NNODES) continue;
                float cr[NREL];
#pragma unroll
                for (int rr = 0; rr < NREL; rr++)
                    cr[rr] = (float)(rp_s[rr * (GM2 + 1) + rl + 1] - rp_s[rr * (GM2 + 1) + rl]);
#pragma unroll
                for (int nt = 0; nt < 2; nt++) {
                    int n = n0 + nt * 16 + lm;
                    float b = 0.f;
#pragma unroll
                    for (int rr = 0; rr < NREL; rr++) b += cr[rr] * bias_s[rr * HID + n];
                    HoutF[(size_t)d * HID + n] = acc[mt][nt][reg] + b;
                }
            }
        }
    }
}

// ---------------- driver ----------------

extern "C" void kernel_launch(void* const* d_in, const int* in_sizes, int n_in,
                              void* d_out, int out_size, void* d_ws, size_t ws_size,
                              hipStream_t stream) {
    const int*   edge_index = (const int*)d_in[0];   // [2, NEDGES]: row0=dest, row1=src
    const int*   etype      = (const int*)d_in[1];
    const float* emb        = (const float*)d_in[2];
    const float* W          = (const float*)d_in[3]; // [3,9,128,128]
    const float* Bias       = (const float*)d_in[4]; // [3,9,128]
    float*       out        = (float*)d_out;

    const int* dst  = edge_index;
    const int* srcA = edge_index + NEDGES;

    // ws layout
    short* Ebf  = (short*)d_ws;                             // 50000*128 bf16
    short* HbfA = Ebf  + (size_t)NNODES * HID;              // 50000*128 bf16
    short* HbfB = HbfA + (size_t)NNODES * HID;              // 50000*128 bf16
    short* Wt2  = HbfB + (size_t)NNODES * HID;              // 3*128*1152 bf16
    int*   bsrc     = (int*)(Wt2 + (size_t)NLAYERS * HID * KTOT);
    int*   bins     = bsrc + NEDGES + 8;                    // +8 pad (lookahead reads)
    int*   cursor   = bins + NBINS;
    int*   rowptr   = cursor + NBINS;                       // NBINS+1
    int*   blocksum = rowptr + NBINS + 1;
    int*   blockoff = blocksum + NBLK;

    hipMemsetAsync(bins, 0, NBINS * sizeof(int), stream);
    prep_kernel<<<HIST_BLKS + EMB_BLKS + W_BLKS, 256, 0, stream>>>(
        dst, etype, bins, emb, Ebf, W, Wt2);
    scan_pass1<<<NBLK, 256, 0, stream>>>(bins, blocksum);
    scan_pass2<<<1, 512, 0, stream>>>(blocksum, blockoff, rowptr);
    scan_pass3<<<NBLK, 256, 0, stream>>>(bins, blockoff, rowptr, cursor);
    place_kernel<<<(NEDGES + 255) / 256, 256, 0, stream>>>(dst, srcA, etype, cursor, bsrc);

    const int nblocks = (NNODES + GM2 - 1) / GM2;   // 1563
    const short* Hin = Ebf;
    for (int l = 0; l < NLAYERS; l++) {
        int last = (l + 1 == NLAYERS);
        short* Hout = (l == 0) ? HbfA : HbfB;       // alternate; never in-place
        if (l == 2) Hout = HbfA;                    // unused on last layer
        const short* Wtl = Wt2 + (size_t)l * HID * KTOT;
        const float* Bl  = Bias + (size_t)l * NREL * HID;
        fused_kernel<<<nblocks, 256, 0, stream>>>(
            Hin, Wtl, Bl, rowptr, bsrc, Hout, out, last);
        Hin = Hout;
    }
}

// Round 5
// 438.705 us; speedup vs baseline: 3.6750x; 1.1226x over previous
//
#include <hip/hip_runtime.h>

#define NNODES 50000
#define HID 128
#define NREL 9
#define NLAYERS 3
#define NEDGES 600000

#define NBINS (NREL * NNODES)          // 450000, bin = r*NNODES + d  (r-major)
#define SCAN_CHUNK 1024
#define NBLK ((NBINS + SCAN_CHUNK - 1) / SCAN_CHUNK)   // 440

#define KTOT (NREL * HID)               // 1152
#define GM2 32                          // fused M-tile -> 1563 blocks
#define FPITCH 136                      // panel/Et pitch in shorts (272 B rows, 2-way banks = free)

// prep_kernel block ranges
#define HIST_BLKS ((NEDGES + 255) / 256)            // 2344
#define EMB_BLKS  ((NNODES * HID / 8) / 256)        // 3125
#define W_BLKS    (NLAYERS * NREL)                  // 27

typedef __attribute__((ext_vector_type(8))) short short8;
typedef __attribute__((ext_vector_type(4))) float f32x4;

__device__ __forceinline__ short f2bf(float f) {
    union { float f; unsigned u; } c; c.f = f;
    unsigned r = c.u + 0x7fff + ((c.u >> 16) & 1);   // RNE
    return (short)(r >> 16);
}
__device__ __forceinline__ float bf2f(short v) {
    return __uint_as_float(((unsigned)(unsigned short)v) << 16);
}

// ---------------- prep: histogram + emb convert + W convert (one dispatch) ----------------
// Wt2[l][n][r*128+kk] = bf16(W[l][r][kk][n])   (r-major K)

__global__ __launch_bounds__(256) void prep_kernel(const int* __restrict__ dst,
                                                   const int* __restrict__ etype,
                                                   int* __restrict__ bins,
                                                   const float* __restrict__ E,
                                                   short* __restrict__ Ebf,
                                                   const float* __restrict__ W,
                                                   short* __restrict__ Wt2) {
    int b = blockIdx.x, tid = threadIdx.x;
    if (b < HIST_BLKS) {
        int e = b * 256 + tid;
        if (e < NEDGES) {
            int bin = etype[e] * NNODES + dst[e];
            atomicAdd(&bins[bin], 1);
        }
    } else if (b < HIST_BLKS + EMB_BLKS) {
        int gid = (b - HIST_BLKS) * 256 + tid;
        const float* p = E + (size_t)gid * 8;
        float4 v0 = *(const float4*)p;
        float4 v1 = *(const float4*)(p + 4);
        short8 o = {f2bf(v0.x), f2bf(v0.y), f2bf(v0.z), f2bf(v0.w),
                    f2bf(v1.x), f2bf(v1.y), f2bf(v1.z), f2bf(v1.w)};
        *(short8*)(Ebf + (size_t)gid * 8) = o;
    } else {
        int lr = b - HIST_BLKS - EMB_BLKS;
        int l = lr / NREL, r = lr - l * NREL;
        const float* w = W + (size_t)lr * HID * HID;
        short* o = Wt2 + (size_t)l * HID * KTOT;
#pragma unroll 4
        for (int i = 0; i < 64; i++) {
            int elem = i * 256 + tid;
            int kk = elem >> 7, n = elem & 127;
            o[(size_t)n * KTOT + r * HID + kk] = f2bf(w[elem]);
        }
    }
}

// ---------------- scans ----------------

__global__ __launch_bounds__(256) void scan_pass1(const int* __restrict__ bins,
                                                  int* __restrict__ blocksum) {
    __shared__ int red[256];
    int b = blockIdx.x, t = threadIdx.x;
    int i0 = b * SCAN_CHUNK + t * 4;
    int s = 0;
#pragma unroll
    for (int k = 0; k < 4; k++)
        if (i0 + k < NBINS) s += bins[i0 + k];
    red[t] = s;
    __syncthreads();
    for (int off = 128; off > 0; off >>= 1) {
        if (t < off) red[t] += red[t + off];
        __syncthreads();
    }
    if (t == 0) blocksum[b] = red[0];
}

__global__ __launch_bounds__(512) void scan_pass2(const int* __restrict__ blocksum,
                                                  int* __restrict__ blockoff,
                                                  int* __restrict__ rowptr) {
    __shared__ int s[512];
    int t = threadIdx.x;
    int v = (t < NBLK) ? blocksum[t] : 0;
    s[t] = v;
    __syncthreads();
    for (int off = 1; off < 512; off <<= 1) {
        int x = (t >= off) ? s[t - off] : 0;
        __syncthreads();
        s[t] += x;
        __syncthreads();
    }
    if (t < NBLK) blockoff[t] = s[t] - v;
    if (t == 0) rowptr[NBINS] = NEDGES;
}

__global__ __launch_bounds__(256) void scan_pass3(const int* __restrict__ bins,
                                                  const int* __restrict__ blockoff,
                                                  int* __restrict__ rowptr,
                                                  int* __restrict__ cursor) {
    __shared__ int sc[256];
    int b = blockIdx.x, t = threadIdx.x;
    int i0 = b * SCAN_CHUNK + t * 4;
    int v[4], p[4];
    int s = 0;
#pragma unroll
    for (int k = 0; k < 4; k++) {
        v[k] = (i0 + k < NBINS) ? bins[i0 + k] : 0;
        p[k] = s;
        s += v[k];
    }
    sc[t] = s;
    __syncthreads();
    for (int off = 1; off < 256; off <<= 1) {
        int x = (t >= off) ? sc[t - off] : 0;
        __syncthreads();
        sc[t] += x;
        __syncthreads();
    }
    int base = blockoff[b] + (sc[t] - s);
#pragma unroll
    for (int k = 0; k < 4; k++) {
        if (i0 + k < NBINS) {
            rowptr[i0 + k] = base + p[k];
            cursor[i0 + k] = base + p[k];
        }
    }
}

__global__ void place_kernel(const int* __restrict__ dst, const int* __restrict__ src,
                             const int* __restrict__ etype,
                             int* __restrict__ cursor, int* __restrict__ bsrc) {
    int e = blockIdx.x * blockDim.x + threadIdx.x;
    if (e < NEDGES) {
        int bin = etype[e] * NNODES + dst[e];
        int pos = atomicAdd(&cursor[bin], 1);
        bsrc[pos] = src[e];
    }
}

// ---------------- fused layer: gather (4-wide edge groups) + GEMM + bias + act ----------------
// Round-2 skeleton: per block 32 dest rows, dbuf bf16 panel, ONE barrier/relation.
// Gather inner loop: per bin, 4 index loads -> 4 H-row loads ALL in flight ->
// masked accumulate (1 idx latency + 1 row latency per group; 91% of bins = 1 group).
// Next relation's first 4 indices prefetched before the barrier (resolved during MFMA).
// Index loads pad-safe (bsrc +8 pad); index VALUES clamped to s0 before addressing;
// masked lanes multiply valid finite H data by 0 (no NaN/OOB).
// Wave shape 32Mx32N; C mapping: row = mt*16+lq*4+reg, col = n0+nt*16+lm (verified).

__global__ __launch_bounds__(256, 4) void fused_kernel(const short* __restrict__ Hin,
                                                       const short* __restrict__ Wt2l,
                                                       const float* __restrict__ Bias, // [9][128]
                                                       const int* __restrict__ rowptr,
                                                       const int* __restrict__ bsrc,
                                                       short* __restrict__ HoutBf,     // !last
                                                       float* __restrict__ HoutF,      // last
                                                       int last) {
    __shared__ short As[2][GM2 * FPITCH];         // 2 x 8704 B, [0] reused as Et
    __shared__ int   rp_s[NREL * (GM2 + 1)];      // 297 ints
    __shared__ float bias_s[NREL * HID];          // 4608 B

    int tid  = threadIdx.x;
    int wave = tid >> 6, lane = tid & 63;
    int lm = lane & 15, lq = lane >> 4;
    int row0 = blockIdx.x * GM2;
    int n0   = wave * 32;                 // wave's N base
    int grow = tid >> 3;                  // 0..31 dest row (8 lanes/row -> max-of-8 per wave)
    int gcc  = tid & 7;                   // 16-col group

    // ---- prologue: prefetch rel-0 first 4 indices (pad-safe raw loads) ----
    int d0  = row0 + grow;
    int dc  = (d0     > NNODES) ? NNODES : d0;
    int dc1 = (d0 + 1 > NNODES) ? NNODES : (d0 + 1);
    int rs0 = rowptr[dc];
    int re0 = rowptr[dc1];
    int pf0 = 0, pf1 = 0, pf2 = 0, pf3 = 0;
    if (rs0 < re0) {
        pf0 = bsrc[rs0];
        pf1 = bsrc[rs0 + 1];
        pf2 = bsrc[rs0 + 2];
        pf3 = bsrc[rs0 + 3];
    }

    // stage rowptr spans (9 x 33) and bias
    for (int i = tid; i < NREL * (GM2 + 1); i += 256) {
        int r = i / (GM2 + 1), o = i - r * (GM2 + 1);
        int d = row0 + o; if (d > NNODES) d = NNODES;   // clamp -> cnt 0 for pad rows
        rp_s[i] = rowptr[r * NNODES + d];
    }
    for (int i = tid; i < NREL * HID; i += 256) bias_s[i] = Bias[i];

    f32x4 acc[2][2];
#pragma unroll
    for (int a = 0; a < 2; a++)
#pragma unroll
        for (int b = 0; b < 2; b++) acc[a][b] = (f32x4){0.f, 0.f, 0.f, 0.f};

    __syncthreads();

    const short* wb = Wt2l + (size_t)(n0 + lm) * KTOT + lq * 8;
    const short* hb = Hin + gcc * 16;

    for (int r = 0; r < NREL; r++) {
        short* Ap = &As[r & 1][0];

        // ---- B prefetch: 8 independent 16B loads, consumed after the barrier ----
        short8 bfr[2][4];
#pragma unroll
        for (int nt = 0; nt < 2; nt++)
#pragma unroll
            for (int ks = 0; ks < 4; ks++)
                bfr[nt][ks] = *(const short8*)(wb + (size_t)nt * 16 * KTOT + r * HID + ks * 32);

        // ---- gather: 4-wide edge groups, register accumulation ----
        int rs = rp_s[r * (GM2 + 1) + grow];
        int re = rp_s[r * (GM2 + 1) + grow + 1];
        float ga[16];
#pragma unroll
        for (int i = 0; i < 16; i++) ga[i] = 0.f;

        int j = rs;
        if (j < re) {
            // first group: indices already prefetched
            int rem = re - j;
            int s0 = pf0;
            int s1 = (rem > 1) ? pf1 : s0;
            int s2 = (rem > 2) ? pf2 : s0;
            int s3 = (rem > 3) ? pf3 : s0;
            const short8* p0 = (const short8*)(hb + (size_t)s0 * HID);
            const short8* p1 = (const short8*)(hb + (size_t)s1 * HID);
            const short8* p2 = (const short8*)(hb + (size_t)s2 * HID);
            const short8* p3 = (const short8*)(hb + (size_t)s3 * HID);
            short8 a0 = p0[0], a1 = p0[1];
            short8 b0 = p1[0], b1 = p1[1];
            short8 c0 = p2[0], c1 = p2[1];
            short8 d0v = p3[0], d1v = p3[1];
            float m1 = (rem > 1) ? 1.f : 0.f;
            float m2 = (rem > 2) ? 1.f : 0.f;
            float m3 = (rem > 3) ? 1.f : 0.f;
#pragma unroll
            for (int k = 0; k < 8; k++) {
                ga[k]     += (bf2f(a0[k]) + m1 * bf2f(b0[k])) + (m2 * bf2f(c0[k]) + m3 * bf2f(d0v[k]));
                ga[k + 8] += (bf2f(a1[k]) + m1 * bf2f(b1[k])) + (m2 * bf2f(c1[k]) + m3 * bf2f(d1v[k]));
            }
            j += 4;
        }
        for (; j < re; j += 4) {
            // rare long-bin path (bins > 4 edges): raw idx loads are pad-safe,
            // values clamped before addressing
            int rem = re - j;
            int s0 = bsrc[j];
            int t1 = bsrc[j + 1];
            int t2 = bsrc[j + 2];
            int t3 = bsrc[j + 3];
            int s1 = (rem > 1) ? t1 : s0;
            int s2 = (rem > 2) ? t2 : s0;
            int s3 = (rem > 3) ? t3 : s0;
            const short8* p0 = (const short8*)(hb + (size_t)s0 * HID);
            const short8* p1 = (const short8*)(hb + (size_t)s1 * HID);
            const short8* p2 = (const short8*)(hb + (size_t)s2 * HID);
            const short8* p3 = (const short8*)(hb + (size_t)s3 * HID);
            short8 a0 = p0[0], a1 = p0[1];
            short8 b0 = p1[0], b1 = p1[1];
            short8 c0 = p2[0], c1 = p2[1];
            short8 d0v = p3[0], d1v = p3[1];
            float m1 = (rem > 1) ? 1.f : 0.f;
            float m2 = (rem > 2) ? 1.f : 0.f;
            float m3 = (rem > 3) ? 1.f : 0.f;
#pragma unroll
            for (int k = 0; k < 8; k++) {
                ga[k]     += (bf2f(a0[k]) + m1 * bf2f(b0[k])) + (m2 * bf2f(c0[k]) + m3 * bf2f(d0v[k]));
                ga[k + 8] += (bf2f(a1[k]) + m1 * bf2f(b1[k])) + (m2 * bf2f(c1[k]) + m3 * bf2f(d1v[k]));
            }
        }

        // ---- convert + LDS write (own slot; dbuf -> no WAR hazard) ----
        {
            short8 o0, o1;
#pragma unroll
            for (int i = 0; i < 8; i++) {
                o0[i] = f2bf(ga[i]);
                o1[i] = f2bf(ga[i + 8]);
            }
            short8* ap = (short8*)&Ap[grow * FPITCH + gcc * 16];
            ap[0] = o0; ap[1] = o1;
        }

        // ---- prefetch next relation's first 4 indices (resolve during barrier+MFMA) ----
        if (r + 1 < NREL) {
            int nrs = rp_s[(r + 1) * (GM2 + 1) + grow];
            int nre = rp_s[(r + 1) * (GM2 + 1) + grow + 1];
            if (nrs < nre) {
                pf0 = bsrc[nrs];
                pf1 = bsrc[nrs + 1];
                pf2 = bsrc[nrs + 2];
                pf3 = bsrc[nrs + 3];
            }
        }
        __syncthreads();

        // ---- MFMA phase: A from LDS, B already in registers ----
#pragma unroll
        for (int ks = 0; ks < 4; ks++) {
            short8 af0 = *(const short8*)&Ap[(lm     ) * FPITCH + ks * 32 + lq * 8];
            short8 af1 = *(const short8*)&Ap[(lm + 16) * FPITCH + ks * 32 + lq * 8];
            __builtin_amdgcn_s_setprio(1);
            acc[0][0] = __builtin_amdgcn_mfma_f32_16x16x32_bf16(af0, bfr[0][ks], acc[0][0], 0, 0, 0);
            acc[1][0] = __builtin_amdgcn_mfma_f32_16x16x32_bf16(af1, bfr[0][ks], acc[1][0], 0, 0, 0);
            acc[0][1] = __builtin_amdgcn_mfma_f32_16x16x32_bf16(af0, bfr[1][ks], acc[0][1], 0, 0, 0);
            acc[1][1] = __builtin_amdgcn_mfma_f32_16x16x32_bf16(af1, bfr[1][ks], acc[1][1], 0, 0, 0);
            __builtin_amdgcn_s_setprio(0);
        }
        // no trailing barrier: next relation writes the OTHER buffer
    }

    __syncthreads();   // last MFMA read As[0] (r=8); safe to reuse as Et after this

    // ---- epilogue: counts-weighted bias, activation, store ----
    if (!last) {
        short (*Et)[FPITCH] = (short(*)[FPITCH])&As[0][0];
#pragma unroll
        for (int mt = 0; mt < 2; mt++) {
#pragma unroll
            for (int reg = 0; reg < 4; reg++) {
                int rl = mt * 16 + lq * 4 + reg;
                float cr[NREL];
#pragma unroll
                for (int rr = 0; rr < NREL; rr++)
                    cr[rr] = (float)(rp_s[rr * (GM2 + 1) + rl + 1] - rp_s[rr * (GM2 + 1) + rl]);
#pragma unroll
                for (int nt = 0; nt < 2; nt++) {
                    int n = n0 + nt * 16 + lm;
                    float b = 0.f;
#pragma unroll
                    for (int rr = 0; rr < NREL; rr++) b += cr[rr] * bias_s[rr * HID + n];
                    float o = fmaxf(acc[mt][nt][reg] + b, 0.f);
                    Et[rl][n] = f2bf(o);
                }
            }
        }
        __syncthreads();
#pragma unroll
        for (int i = 0; i < 2; i++) {
            int p = i * 256 + tid;
            int row = p >> 4, cc = p & 15;
            int d = row0 + row;
            if (d < NNODES)
                *(short8*)(HoutBf + (size_t)d * HID + cc * 8) = *(const short8*)&Et[row][cc * 8];
        }
    } else {
#pragma unroll
        for (int mt = 0; mt < 2; mt++) {
#pragma unroll
            for (int reg = 0; reg < 4; reg++) {
                int rl = mt * 16 + lq * 4 + reg;
                int d  = row0 + rl;
                if (d >= NNODES) continue;
                float cr[NREL];
#pragma unroll
                for (int rr = 0; rr < NREL; rr++)
                    cr[rr] = (float)(rp_s[rr * (GM2 + 1) + rl + 1] - rp_s[rr * (GM2 + 1) + rl]);
#pragma unroll
                for (int nt = 0; nt < 2; nt++) {
                    int n = n0 + nt * 16 + lm;
                    float b = 0.f;
#pragma unroll
                    for (int rr = 0; rr < NREL; rr++) b += cr[rr] * bias_s[rr * HID + n];
                    HoutF[(size_t)d * HID + n] = acc[mt][nt][reg] + b;
                }
            }
        }
    }
}

// ---------------- driver ----------------

extern "C" void kernel_launch(void* const* d_in, const int* in_sizes, int n_in,
                              void* d_out, int out_size, void* d_ws, size_t ws_size,
                              hipStream_t stream) {
    const int*   edge_index = (const int*)d_in[0];   // [2, NEDGES]: row0=dest, row1=src
    const int*   etype      = (const int*)d_in[1];
    const float* emb        = (const float*)d_in[2];
    const float* W          = (const float*)d_in[3]; // [3,9,128,128]
    const float* Bias       = (const float*)d_in[4]; // [3,9,128]
    float*       out        = (float*)d_out;

    const int* dst  = edge_index;
    const int* srcA = edge_index + NEDGES;

    // ws layout
    short* Ebf  = (short*)d_ws;                             // 50000*128 bf16
    short* HbfA = Ebf  + (size_t)NNODES * HID;              // 50000*128 bf16
    short* HbfB = HbfA + (size_t)NNODES * HID;              // 50000*128 bf16
    short* Wt2  = HbfB + (size_t)NNODES * HID;              // 3*128*1152 bf16
    int*   bsrc     = (int*)(Wt2 + (size_t)NLAYERS * HID * KTOT);
    int*   bins     = bsrc + NEDGES + 8;                    // +8 pad (idx prefetch reads)
    int*   cursor   = bins + NBINS;
    int*   rowptr   = cursor + NBINS;                       // NBINS+1
    int*   blocksum = rowptr + NBINS + 1;
    int*   blockoff = blocksum + NBLK;

    hipMemsetAsync(bins, 0, NBINS * sizeof(int), stream);
    prep_kernel<<<HIST_BLKS + EMB_BLKS + W_BLKS, 256, 0, stream>>>(
        dst, etype, bins, emb, Ebf, W, Wt2);
    scan_pass1<<<NBLK, 256, 0, stream>>>(bins, blocksum);
    scan_pass2<<<1, 512, 0, stream>>>(blocksum, blockoff, rowptr);
    scan_pass3<<<NBLK, 256, 0, stream>>>(bins, blockoff, rowptr, cursor);
    place_kernel<<<(NEDGES + 255) / 256, 256, 0, stream>>>(dst, srcA, etype, cursor, bsrc);

    const int nblocks = (NNODES + GM2 - 1) / GM2;   // 1563
    const short* Hin = Ebf;
    for (int l = 0; l < NLAYERS; l++) {
        int last = (l + 1 == NLAYERS);
        short* Hout = (l == 0) ? HbfA : HbfB;       // alternate; never in-place
        if (l == 2) Hout = HbfA;                    // unused on last layer
        const short* Wtl = Wt2 + (size_t)l * HID * KTOT;
        const float* Bl  = Bias + (size_t)l * NREL * HID;
        fused_kernel<<<nblocks, 256, 0, stream>>>(
            Hin, Wtl, Bl, rowptr, bsrc, Hout, out, last);
        Hin = Hout;
    }
}